// Round 9
// baseline (12400.913 us; speedup 1.0000x reference)
//
#include <hip/hip_runtime.h>
#include <hip/hip_bf16.h>
#include <math.h>
#include <stdint.h>

#define NLAYERS 30
#define BB 16
#define LL 32768
#define SEG 256
#define NT (SEG / 16)

#define SS 16384.0f
#define SSI (1.0f / 16384.0f)

typedef __attribute__((ext_vector_type(8))) short bf16x8;
typedef __attribute__((ext_vector_type(8))) short s16x8;
typedef __attribute__((ext_vector_type(4))) float f32x4;

__device__ inline float bf2f(ushort u) {
    union { uint i; float f; } v; v.i = ((uint)u) << 16; return v.f;
}
__device__ inline ushort f2bf(float f) {  // RNE
    uint u = __float_as_uint(f);
    return (ushort)((u + 0x7FFFu + ((u >> 16) & 1u)) >> 16);
}
__device__ inline uint cvtpk(float lo, float hi) {  // (bf16(hi)<<16)|bf16(lo)
    uint r;
    asm("v_cvt_pk_bf16_f32 %0, %1, %2" : "=v"(r) : "v"(lo), "v"(hi));
    return r;
}

// ---------------- embedding MLP: t[b,512] ----------------
__global__ void emb_kernel(const int* __restrict__ step, const float* __restrict__ emb,
                           const float* __restrict__ W1, const float* __restrict__ b1,
                           const float* __restrict__ W2, const float* __restrict__ b2,
                           float* __restrict__ t_out) {
    int b = blockIdx.x, j = threadIdx.x;
    __shared__ float e[128];
    __shared__ float t1[512];
    int s = step[b];
    if (j < 128) e[j] = emb[s * 128 + j];
    __syncthreads();
    float acc = b1[j];
    const float* w = W1 + j * 128;
    for (int k = 0; k < 128; ++k) acc += w[k] * e[k];
    t1[j] = acc / (1.f + __expf(-acc));
    __syncthreads();
    float acc2 = b2[j];
    const float* w2 = W2 + j * 512;
    for (int k = 0; k < 512; ++k) acc2 += w2[k] * t1[k];
    t_out[b * 512 + j] = acc2 / (1.f + __expf(-acc2));
}

// ---------------- dp[i,b,c] = t[b] . diff_W[i,c,:] + diff_b[i,c] ----------------
__global__ void dp_kernel(const float* __restrict__ t, const float* __restrict__ diff_W,
                          const float* __restrict__ diff_b, float* __restrict__ dp) {
    int i = blockIdx.x, b = blockIdx.y, c = threadIdx.x;  // 64 threads
    __shared__ float ts[512];
    for (int k = c; k < 512; k += 64) ts[k] = t[b * 512 + k];
    __syncthreads();
    const float* w = diff_W + (size_t)(i * 64 + c) * 512;
    float acc = diff_b[i * 64 + c];
    for (int k = 0; k < 512; ++k) acc += w[k] * ts[k];
    dp[(i * BB + b) * 64 + c] = acc;
}

// ---------------- weight shuffles into MFMA fragment order (bf16) ----------------
__global__ void prep_w_kernel(const float* __restrict__ dconv_W, ushort* __restrict__ wB,
                              const float* __restrict__ out_W, ushort* __restrict__ oB,
                              const float* __restrict__ Wo1, ushort* __restrict__ Wo1B) {
    int idx = blockIdx.x * 256 + threadIdx.x;
    if (idx < 30 * 8 * 6 * 512) {
        int i = idx / 24576;
        int r = idx % 24576;
        int mt = r / 3072;
        int s = (r / 512) % 6;
        int lane = (r >> 3) & 63;
        int j = r & 7;
        int o = mt * 16 + (lane & 15);
        int tap = s >> 1;
        int c = (s & 1) * 32 + (lane >> 4) * 8 + j;
        wB[idx] = f2bf(dconv_W[((size_t)(i * 128 + o) * 64 + c) * 3 + tap]);
    }
    if (idx < 30 * 8 * 2 * 512) {
        int i = idx / 8192;
        int r = idx % 8192;
        int mt = r / 1024;
        int s = (r / 512) % 2;
        int lane = (r >> 3) & 63;
        int j = r & 7;
        int o = mt * 16 + (lane & 15);
        int c = s * 32 + (lane >> 4) * 8 + j;
        oB[idx] = f2bf(out_W[(size_t)(i * 128 + o) * 64 + c]);
    }
    if (idx < 4 * 2 * 512) {
        int mt = idx / 1024;
        int s = (idx / 512) % 2;
        int lane = (idx >> 3) & 63;
        int j = idx & 7;
        int o = mt * 16 + (lane & 15);
        int c = s * 32 + (lane >> 4) * 8 + j;
        const float hscale = SSI * 0.18257418583505537115f;  // SSI / sqrt(30)
        Wo1B[idx] = f2bf(Wo1[o * 64 + c] * hscale);
    }
}

// ---------------- bias3[i][b][{full,left,right}][128] ----------------
__global__ void bias3_kernel(const float* __restrict__ dp, const float* __restrict__ dconv_W,
                             const float* __restrict__ dconv_b, float* __restrict__ bias3) {
    int i = blockIdx.x, b = blockIdx.y, o = threadIdx.x;  // 128 threads
    __shared__ float sdp[64];
    if (o < 64) sdp[o] = dp[(i * BB + b) * 64 + o];
    __syncthreads();
    const float* wrow = dconv_W + (size_t)(i * 128 + o) * 192;
    float f = 0.f, lft = 0.f, rgt = 0.f;
    for (int c = 0; c < 64; ++c) {
        float w0 = wrow[c * 3 + 0], w1 = wrow[c * 3 + 1], w2 = wrow[c * 3 + 2];
        float dv = sdp[c];
        f += dv * (w0 + w1 + w2);
        lft += dv * w0;
        rgt += dv * w2;
    }
    float* dst = bias3 + (size_t)(i * BB + b) * 384;
    dst[o] = f + dconv_b[i * 128 + o];
    dst[128 + o] = lft;
    dst[256 + o] = rgt;
}

// ---------------- input projection -> x[b][l][c] bf16 ----------------
__global__ void inproj_kernel(const float* __restrict__ audio, const float* __restrict__ Win,
                              const float* __restrict__ bin_, ushort* __restrict__ x) {
    int idx = blockIdx.x * 256 + threadIdx.x;  // B*L*8
    int c8 = idx & 7;
    int l = (idx >> 3) & (LL - 1);
    int b = idx >> 18;
    float a = audio[(size_t)b * LL + l];
    ushort us[8];
    #pragma unroll
    for (int cc = 0; cc < 8; ++cc) {
        int c = c8 * 8 + cc;
        float v = a * Win[c] + bin_[c];
        us[cc] = f2bf(v > 0.f ? v : 0.f);
    }
    ushort4* dst = (ushort4*)(x + ((size_t)b * LL + l) * 64 + c8 * 8);
    dst[0] = make_ushort4(us[0], us[1], us[2], us[3]);
    dst[1] = make_ushort4(us[4], us[5], us[6], us[7]);
}

// ---------------- fused residual layer: 2 sub-tiles per barrier, pipelined ----------------
__global__ __launch_bounds__(256, 4) void layer_fused(
    const ushort* __restrict__ xin, ushort* __restrict__ xout, int16_t* __restrict__ skip,
    const ushort* __restrict__ wB,    // [8][6][64][8] this layer
    const ushort* __restrict__ oB,    // [8][2][64][8] this layer
    const float* __restrict__ bias3,  // [16][3][128] this layer
    const float* __restrict__ out_b,  // [128]
    int d) {
    __shared__ __align__(16) ushort su[2][2][16][72];  // [buf][slot][pos][ch]

    // XCD-aware bijective swizzle: 2048 blocks = 8 XCDs x 256 contiguous
    const int nlin = blockIdx.y * gridDim.x + blockIdx.x;
    const int wgid = (nlin & 7) * 256 + (nlin >> 3);
    const int seg = wgid & (LL / SEG - 1);
    const int b = wgid >> 7;

    const int tid = threadIdx.x;
    const int lane = tid & 63;
    const int p = tid >> 6;
    const int n = lane & 15;
    const int kg = lane >> 4;
    const int rlo = p * 16 + kg * 4;

    bf16x8 A0[6], A1[6], P0[2], P1[2];
    #pragma unroll
    for (int s = 0; s < 6; ++s) {
        A0[s] = *(const bf16x8*)(wB + ((size_t)(p * 6 + s) * 64 + lane) * 8);
        A1[s] = *(const bf16x8*)(wB + ((size_t)((p + 4) * 6 + s) * 64 + lane) * 8);
    }
    #pragma unroll
    for (int s = 0; s < 2; ++s) {
        P0[s] = *(const bf16x8*)(oB + ((size_t)(p * 2 + s) * 64 + lane) * 8);
        P1[s] = *(const bf16x8*)(oB + ((size_t)((p + 4) * 2 + s) * 64 + lane) * 8);
    }
    const float* bb = bias3 + (size_t)b * 384;
    f32x4 bF_lo = *(const f32x4*)(bb + rlo);
    f32x4 bF_hi = *(const f32x4*)(bb + 64 + rlo);
    f32x4 bL_lo = *(const f32x4*)(bb + 128 + rlo);
    f32x4 bL_hi = *(const f32x4*)(bb + 192 + rlo);
    f32x4 bR_lo = *(const f32x4*)(bb + 256 + rlo);
    f32x4 bR_hi = *(const f32x4*)(bb + 320 + rlo);
    f32x4 obL = *(const f32x4*)(out_b + rlo);
    f32x4 obH = *(const f32x4*)(out_b + 64 + rlo);

    const ushort* xb = xin + (size_t)b * LL * 64;
    ushort* xo = xout + (size_t)b * LL * 64;
    int16_t* sb = skip + (size_t)b * LL * 64;
    const float inv_s2 = 0.70710678118654752440f;

#define LOADB(DST, TT)                                                           \
    {                                                                            \
        const int l0_ = seg * SEG + (TT) * 16;                                   \
        _Pragma("unroll")                                                        \
        for (int tap = 0; tap < 3; ++tap) {                                      \
            int lx = l0_ + n + (tap - 1) * d;                                    \
            bool v = (lx >= 0) && (lx < LL);                                     \
            _Pragma("unroll")                                                    \
            for (int h = 0; h < 2; ++h) {                                        \
                bf16x8 bv = {0, 0, 0, 0, 0, 0, 0, 0};                            \
                if (v) bv = *(const bf16x8*)(xb + (size_t)lx * 64 + h * 32 + kg * 8); \
                DST[tap * 2 + h] = bv;                                           \
            }                                                                    \
        }                                                                        \
    }

#define LOADE(XV, SO, TT)                                                        \
    {                                                                            \
        size_t off_ = (size_t)(seg * SEG + (TT) * 16 + n) * 64 + rlo;            \
        XV = *(const ushort4*)(xb + off_);                                       \
        SO = *(const short4*)(sb + off_);                                        \
    }

#define BODY1(TT, BUF, SLOT, BF)                                                 \
    {                                                                            \
        f32x4 accL = {0.f, 0.f, 0.f, 0.f}, accH = {0.f, 0.f, 0.f, 0.f};          \
        _Pragma("unroll")                                                        \
        for (int s = 0; s < 6; ++s) {                                            \
            accL = __builtin_amdgcn_mfma_f32_16x16x32_bf16(A0[s], BF[s], accL, 0, 0, 0); \
            accH = __builtin_amdgcn_mfma_f32_16x16x32_bf16(A1[s], BF[s], accH, 0, 0, 0); \
        }                                                                        \
        const int lx0 = seg * SEG + (TT) * 16 + n;                               \
        float selL = (lx0 < d) ? 1.f : 0.f;                                      \
        float selR = (lx0 >= LL - d) ? 1.f : 0.f;                                \
        float uu[4];                                                             \
        _Pragma("unroll")                                                        \
        for (int j = 0; j < 4; ++j) {                                            \
            float lo = accL[j] + bF_lo[j] - selL * bL_lo[j] - selR * bR_lo[j];   \
            float hi = accH[j] + bF_hi[j] - selL * bL_hi[j] - selR * bR_hi[j];   \
            float tv = 1.f - 2.f / (1.f + __expf(2.f * lo));                     \
            float sv = 1.f / (1.f + __expf(-hi));                                \
            uu[j] = tv * sv;                                                     \
        }                                                                        \
        uint2 uq;                                                                \
        uq.x = cvtpk(uu[0], uu[1]);                                              \
        uq.y = cvtpk(uu[2], uu[3]);                                              \
        *(uint2*)&su[BUF][SLOT][n][rlo] = uq;                                    \
    }

#define BODY2(TT, BUF, SLOT, XV, SO)                                             \
    {                                                                            \
        bf16x8 Bp0 = *(const bf16x8*)&su[BUF][SLOT][n][kg * 8];                  \
        bf16x8 Bp1 = *(const bf16x8*)&su[BUF][SLOT][n][32 + kg * 8];             \
        f32x4 zL = {0.f, 0.f, 0.f, 0.f}, zH = {0.f, 0.f, 0.f, 0.f};              \
        zL = __builtin_amdgcn_mfma_f32_16x16x32_bf16(P0[0], Bp0, zL, 0, 0, 0);   \
        zH = __builtin_amdgcn_mfma_f32_16x16x32_bf16(P1[0], Bp0, zH, 0, 0, 0);   \
        zL = __builtin_amdgcn_mfma_f32_16x16x32_bf16(P0[1], Bp1, zL, 0, 0, 0);   \
        zH = __builtin_amdgcn_mfma_f32_16x16x32_bf16(P1[1], Bp1, zH, 0, 0, 0);   \
        const int lx0 = seg * SEG + (TT) * 16 + n;                               \
        size_t off = (size_t)lx0 * 64 + rlo;                                     \
        float f0 = (bf2f(XV.x) + zL[0] + obL[0]) * inv_s2;                       \
        float f1 = (bf2f(XV.y) + zL[1] + obL[1]) * inv_s2;                       \
        float f2 = (bf2f(XV.z) + zL[2] + obL[2]) * inv_s2;                       \
        float f3 = (bf2f(XV.w) + zL[3] + obL[3]) * inv_s2;                       \
        uint2 xn;                                                                \
        xn.x = cvtpk(f0, f1);                                                    \
        xn.y = cvtpk(f2, f3);                                                    \
        *(uint2*)(xo + off) = xn;                                                \
        short4 sn;                                                               \
        float v;                                                                 \
        v = fminf(fmaxf((float)SO.x * SSI + zH[0] + obH[0], -1.999f), 1.999f);   \
        sn.x = (short)__float2int_rn(v * SS);                                    \
        v = fminf(fmaxf((float)SO.y * SSI + zH[1] + obH[1], -1.999f), 1.999f);   \
        sn.y = (short)__float2int_rn(v * SS);                                    \
        v = fminf(fmaxf((float)SO.z * SSI + zH[2] + obH[2], -1.999f), 1.999f);   \
        sn.z = (short)__float2int_rn(v * SS);                                    \
        v = fminf(fmaxf((float)SO.w * SSI + zH[3] + obH[3], -1.999f), 1.999f);   \
        sn.w = (short)__float2int_rn(v * SS);                                    \
        *(short4*)(sb + off) = sn;                                               \
    }

    bf16x8 FA[6], FB[6];
    ushort4 xvA, xvB;
    short4 soA, soB;
    LOADB(FA, 0)
    LOADB(FB, 1)
    LOADE(xvA, soA, 0)
    LOADE(xvB, soB, 1)
    for (int t = 0; t < NT; t += 2) {
        const int buf = (t >> 1) & 1;
        const int ta = (t + 2 < NT) ? t + 2 : t;
        const int tb = (t + 3 < NT) ? t + 3 : t + 1;
        // phase 1: conv GEMMs + gate -> LDS; refill B-frags for next macro
        BODY1(t, buf, 0, FA)
        LOADB(FA, ta)
        BODY1(t + 1, buf, 1, FB)
        LOADB(FB, tb)
        asm volatile("s_waitcnt lgkmcnt(0)" ::: "memory");
        __builtin_amdgcn_s_barrier();
        asm volatile("" ::: "memory");
        // phase 2: proj GEMMs + epilogue; refill epilogue operands
        BODY2(t, buf, 0, xvA, soA)
        BODY2(t + 1, buf, 1, xvB, soB)
        LOADE(xvA, soA, ta)
        LOADE(xvB, soB, tb)
    }
#undef LOADB
#undef LOADE
#undef BODY1
#undef BODY2
}

// ---------------- output head (MFMA, exact int16 hi/lo split) ----------------
__global__ __launch_bounds__(256) void head_mfma(const int16_t* __restrict__ skip,
                                                 const ushort* __restrict__ Wo1B,  // [4][2][64][8]
                                                 const float* __restrict__ bo1,
                                                 const float* __restrict__ Wo2,
                                                 const float* __restrict__ bo2,
                                                 float* __restrict__ out) {
    const int b = blockIdx.y;
    const int seg = blockIdx.x;  // 1024-pos segment
    const int tid = threadIdx.x;
    const int lane = tid & 63;
    const int w = tid >> 6;
    const int n = lane & 15;
    const int kg = lane >> 4;

    bf16x8 A[4][2];
    #pragma unroll
    for (int mt = 0; mt < 4; ++mt)
        #pragma unroll
        for (int s = 0; s < 2; ++s)
            A[mt][s] = *(const bf16x8*)(Wo1B + ((size_t)(mt * 2 + s) * 64 + lane) * 8);
    f32x4 bo1v[4], wo2v[4];
    #pragma unroll
    for (int mt = 0; mt < 4; ++mt) {
        bo1v[mt] = *(const f32x4*)(bo1 + mt * 16 + kg * 4);
        wo2v[mt] = *(const f32x4*)(Wo2 + mt * 16 + kg * 4);
    }
    const float bo2v = bo2[0];
    const int16_t* sb = skip + (size_t)b * LL * 64;

    for (int t = 0; t < 16; ++t) {
        const int l0 = seg * 1024 + t * 64 + w * 16;
        bf16x8 BH[2], BL[2];
        #pragma unroll
        for (int s = 0; s < 2; ++s) {
            s16x8 v = *(const s16x8*)(sb + (size_t)(l0 + n) * 64 + s * 32 + kg * 8);
            bf16x8 bh, bl;
            #pragma unroll
            for (int e = 0; e < 8; ++e) {
                int sv = (int)v[e];
                int h8 = sv >> 8;
                int l8 = sv - (h8 << 8);
                bh[e] = (short)f2bf((float)h8);
                bl[e] = (short)f2bf((float)l8);
            }
            BH[s] = bh;
            BL[s] = bl;
        }
        f32x4 aH[4], aL[4];
        #pragma unroll
        for (int mt = 0; mt < 4; ++mt) {
            aH[mt] = (f32x4){0.f, 0.f, 0.f, 0.f};
            aL[mt] = (f32x4){0.f, 0.f, 0.f, 0.f};
            #pragma unroll
            for (int s = 0; s < 2; ++s) {
                aH[mt] = __builtin_amdgcn_mfma_f32_16x16x32_bf16(A[mt][s], BH[s], aH[mt], 0, 0, 0);
                aL[mt] = __builtin_amdgcn_mfma_f32_16x16x32_bf16(A[mt][s], BL[s], aL[mt], 0, 0, 0);
            }
        }
        float partial = 0.f;
        #pragma unroll
        for (int mt = 0; mt < 4; ++mt) {
            #pragma unroll
            for (int j = 0; j < 4; ++j) {
                float h = aH[mt][j] * 256.f + aL[mt][j] + bo1v[mt][j];
                partial += (h > 0.f ? h : 0.f) * wo2v[mt][j];
            }
        }
        partial += __shfl_xor(partial, 16, 64);
        partial += __shfl_xor(partial, 32, 64);
        if (kg == 0) out[(size_t)b * LL + l0 + n] = partial + bo2v;
    }
}

extern "C" void kernel_launch(void* const* d_in, const int* in_sizes, int n_in,
                              void* d_out, int out_size, void* d_ws, size_t ws_size,
                              hipStream_t stream) {
    const float* audio = (const float*)d_in[0];
    const int* dstep = (const int*)d_in[1];
    const float* emb = (const float*)d_in[2];
    const float* W1 = (const float*)d_in[3];
    const float* b1 = (const float*)d_in[4];
    const float* W2 = (const float*)d_in[5];
    const float* b2 = (const float*)d_in[6];
    const float* Win = (const float*)d_in[7];
    const float* bin_ = (const float*)d_in[8];
    const float* diff_W = (const float*)d_in[9];
    const float* diff_b = (const float*)d_in[10];
    const float* dconv_W = (const float*)d_in[11];
    const float* dconv_b = (const float*)d_in[12];
    const float* out_W = (const float*)d_in[13];
    const float* out_b = (const float*)d_in[14];
    const float* Wo1 = (const float*)d_in[15];
    const float* bo1 = (const float*)d_in[16];
    const float* Wo2 = (const float*)d_in[17];
    const float* bo2 = (const float*)d_in[18];

    const size_t NACT = (size_t)BB * LL * 64;

    uint8_t* p = (uint8_t*)d_ws;
    ushort* x0 = (ushort*)p;     p += NACT * 2;
    ushort* x1 = (ushort*)p;     p += NACT * 2;
    int16_t* skip = (int16_t*)p; p += NACT * 2;
    float* t = (float*)p;        p += 8192 * 4;
    float* dp = (float*)p;       p += 30720 * 4;
    float* bias3 = (float*)p;    p += 184320 * 4;
    ushort* wB = (ushort*)p;     p += 737280 * 2;
    ushort* oB = (ushort*)p;     p += 245760 * 2;
    ushort* Wo1B = (ushort*)p;   p += 4096 * 2;

    hipMemsetAsync(skip, 0, NACT * 2, stream);
    emb_kernel<<<BB, 512, 0, stream>>>(dstep, emb, W1, b1, W2, b2, t);
    dp_kernel<<<dim3(NLAYERS, BB), 64, 0, stream>>>(t, diff_W, diff_b, dp);
    prep_w_kernel<<<2880, 256, 0, stream>>>(dconv_W, wB, out_W, oB, Wo1, Wo1B);
    bias3_kernel<<<dim3(NLAYERS, BB), 128, 0, stream>>>(dp, dconv_W, dconv_b, bias3);
    inproj_kernel<<<16384, 256, 0, stream>>>(audio, Win, bin_, x0);

    dim3 lgrid(LL / SEG, BB);
    ushort* xin = x0;
    ushort* xout = x1;
    for (int i = 0; i < NLAYERS; ++i) {
        int d = 1 << (i % 10);
        layer_fused<<<lgrid, 256, 0, stream>>>(
            xin, xout, skip, wB + (size_t)i * 24576, oB + (size_t)i * 8192,
            bias3 + (size_t)i * BB * 384, out_b + i * 128, d);
        ushort* tmp = xin; xin = xout; xout = tmp;
    }
    head_mfma<<<dim3(LL / 1024, BB), 256, 0, stream>>>(skip, Wo1B, bo1, Wo2, bo2,
                                                       (float*)d_out);
}

// Round 10
// 4629.538 us; speedup vs baseline: 2.6787x; 2.6787x over previous
//
#include <hip/hip_runtime.h>
#include <hip/hip_bf16.h>
#include <math.h>
#include <stdint.h>

#define NLAYERS 30
#define BB 16
#define LL 32768
#define SEG 256
#define NT (SEG / 16)

#define SS 16384.0f
#define SSI (1.0f / 16384.0f)

typedef __attribute__((ext_vector_type(8))) short bf16x8;
typedef __attribute__((ext_vector_type(8))) short s16x8;
typedef __attribute__((ext_vector_type(4))) float f32x4;

__device__ inline float bf2f(ushort u) {
    union { uint i; float f; } v; v.i = ((uint)u) << 16; return v.f;
}
__device__ inline ushort f2bf(float f) {  // RNE
    uint u = __float_as_uint(f);
    return (ushort)((u + 0x7FFFu + ((u >> 16) & 1u)) >> 16);
}
__device__ inline uint cvtpk(float lo, float hi) {  // (bf16(hi)<<16)|bf16(lo)
    uint r;
    asm("v_cvt_pk_bf16_f32 %0, %1, %2" : "=v"(r) : "v"(lo), "v"(hi));
    return r;
}

// ---------------- embedding MLP: t[b,512] ----------------
__global__ void emb_kernel(const int* __restrict__ step, const float* __restrict__ emb,
                           const float* __restrict__ W1, const float* __restrict__ b1,
                           const float* __restrict__ W2, const float* __restrict__ b2,
                           float* __restrict__ t_out) {
    int b = blockIdx.x, j = threadIdx.x;
    __shared__ float e[128];
    __shared__ float t1[512];
    int s = step[b];
    if (j < 128) e[j] = emb[s * 128 + j];
    __syncthreads();
    float acc = b1[j];
    const float* w = W1 + j * 128;
    for (int k = 0; k < 128; ++k) acc += w[k] * e[k];
    t1[j] = acc / (1.f + __expf(-acc));
    __syncthreads();
    float acc2 = b2[j];
    const float* w2 = W2 + j * 512;
    for (int k = 0; k < 512; ++k) acc2 += w2[k] * t1[k];
    t_out[b * 512 + j] = acc2 / (1.f + __expf(-acc2));
}

// ---------------- dp[i,b,c] = t[b] . diff_W[i,c,:] + diff_b[i,c] ----------------
__global__ void dp_kernel(const float* __restrict__ t, const float* __restrict__ diff_W,
                          const float* __restrict__ diff_b, float* __restrict__ dp) {
    int i = blockIdx.x, b = blockIdx.y, c = threadIdx.x;  // 64 threads
    __shared__ float ts[512];
    for (int k = c; k < 512; k += 64) ts[k] = t[b * 512 + k];
    __syncthreads();
    const float* w = diff_W + (size_t)(i * 64 + c) * 512;
    float acc = diff_b[i * 64 + c];
    for (int k = 0; k < 512; ++k) acc += w[k] * ts[k];
    dp[(i * BB + b) * 64 + c] = acc;
}

// ---------------- weight shuffles into MFMA fragment order (bf16) ----------------
__global__ void prep_w_kernel(const float* __restrict__ dconv_W, ushort* __restrict__ wB,
                              const float* __restrict__ out_W, ushort* __restrict__ oB,
                              const float* __restrict__ Wo1, ushort* __restrict__ Wo1B) {
    int idx = blockIdx.x * 256 + threadIdx.x;
    if (idx < 30 * 8 * 6 * 512) {
        int i = idx / 24576;
        int r = idx % 24576;
        int mt = r / 3072;
        int s = (r / 512) % 6;
        int lane = (r >> 3) & 63;
        int j = r & 7;
        int o = mt * 16 + (lane & 15);
        int tap = s >> 1;
        int c = (s & 1) * 32 + (lane >> 4) * 8 + j;
        wB[idx] = f2bf(dconv_W[((size_t)(i * 128 + o) * 64 + c) * 3 + tap]);
    }
    if (idx < 30 * 8 * 2 * 512) {
        int i = idx / 8192;
        int r = idx % 8192;
        int mt = r / 1024;
        int s = (r / 512) % 2;
        int lane = (r >> 3) & 63;
        int j = r & 7;
        int o = mt * 16 + (lane & 15);
        int c = s * 32 + (lane >> 4) * 8 + j;
        oB[idx] = f2bf(out_W[(size_t)(i * 128 + o) * 64 + c]);
    }
    if (idx < 4 * 2 * 512) {
        int mt = idx / 1024;
        int s = (idx / 512) % 2;
        int lane = (idx >> 3) & 63;
        int j = idx & 7;
        int o = mt * 16 + (lane & 15);
        int c = s * 32 + (lane >> 4) * 8 + j;
        const float hscale = SSI * 0.18257418583505537115f;  // SSI / sqrt(30)
        Wo1B[idx] = f2bf(Wo1[o * 64 + c] * hscale);
    }
}

// ---------------- bias3[i][b][{full,left,right}][128] ----------------
__global__ void bias3_kernel(const float* __restrict__ dp, const float* __restrict__ dconv_W,
                             const float* __restrict__ dconv_b, float* __restrict__ bias3) {
    int i = blockIdx.x, b = blockIdx.y, o = threadIdx.x;  // 128 threads
    __shared__ float sdp[64];
    if (o < 64) sdp[o] = dp[(i * BB + b) * 64 + o];
    __syncthreads();
    const float* wrow = dconv_W + (size_t)(i * 128 + o) * 192;
    float f = 0.f, lft = 0.f, rgt = 0.f;
    for (int c = 0; c < 64; ++c) {
        float w0 = wrow[c * 3 + 0], w1 = wrow[c * 3 + 1], w2 = wrow[c * 3 + 2];
        float dv = sdp[c];
        f += dv * (w0 + w1 + w2);
        lft += dv * w0;
        rgt += dv * w2;
    }
    float* dst = bias3 + (size_t)(i * BB + b) * 384;
    dst[o] = f + dconv_b[i * 128 + o];
    dst[128 + o] = lft;
    dst[256 + o] = rgt;
}

// ---------------- input projection -> x[b][l][c] bf16 ----------------
__global__ void inproj_kernel(const float* __restrict__ audio, const float* __restrict__ Win,
                              const float* __restrict__ bin_, ushort* __restrict__ x) {
    int idx = blockIdx.x * 256 + threadIdx.x;  // B*L*8
    int c8 = idx & 7;
    int l = (idx >> 3) & (LL - 1);
    int b = idx >> 18;
    float a = audio[(size_t)b * LL + l];
    ushort us[8];
    #pragma unroll
    for (int cc = 0; cc < 8; ++cc) {
        int c = c8 * 8 + cc;
        float v = a * Win[c] + bin_[c];
        us[cc] = f2bf(v > 0.f ? v : 0.f);
    }
    ushort4* dst = (ushort4*)(x + ((size_t)b * LL + l) * 64 + c8 * 8);
    dst[0] = make_ushort4(us[0], us[1], us[2], us[3]);
    dst[1] = make_ushort4(us[4], us[5], us[6], us[7]);
}

// ---------------- fused residual layer: 2 sub-tiles per barrier, pipelined ----------------
__global__ __launch_bounds__(256) void layer_fused(
    const ushort* __restrict__ xin, ushort* __restrict__ xout, int16_t* __restrict__ skip,
    const ushort* __restrict__ wB,    // [8][6][64][8] this layer
    const ushort* __restrict__ oB,    // [8][2][64][8] this layer
    const float* __restrict__ bias3,  // [16][3][128] this layer
    const float* __restrict__ out_b,  // [128]
    int d) {
    __shared__ __align__(16) ushort su[2][2][16][72];  // [buf][slot][pos][ch]

    const int b = blockIdx.y;
    const int seg = blockIdx.x;

    const int tid = threadIdx.x;
    const int lane = tid & 63;
    const int p = tid >> 6;
    const int n = lane & 15;
    const int kg = lane >> 4;
    const int rlo = p * 16 + kg * 4;

    bf16x8 A0[6], A1[6], P0[2], P1[2];
    #pragma unroll
    for (int s = 0; s < 6; ++s) {
        A0[s] = *(const bf16x8*)(wB + ((size_t)(p * 6 + s) * 64 + lane) * 8);
        A1[s] = *(const bf16x8*)(wB + ((size_t)((p + 4) * 6 + s) * 64 + lane) * 8);
    }
    #pragma unroll
    for (int s = 0; s < 2; ++s) {
        P0[s] = *(const bf16x8*)(oB + ((size_t)(p * 2 + s) * 64 + lane) * 8);
        P1[s] = *(const bf16x8*)(oB + ((size_t)((p + 4) * 2 + s) * 64 + lane) * 8);
    }
    const float* bb = bias3 + (size_t)b * 384;
    f32x4 bF_lo = *(const f32x4*)(bb + rlo);
    f32x4 bF_hi = *(const f32x4*)(bb + 64 + rlo);
    f32x4 bL_lo = *(const f32x4*)(bb + 128 + rlo);
    f32x4 bL_hi = *(const f32x4*)(bb + 192 + rlo);
    f32x4 bR_lo = *(const f32x4*)(bb + 256 + rlo);
    f32x4 bR_hi = *(const f32x4*)(bb + 320 + rlo);
    f32x4 obL = *(const f32x4*)(out_b + rlo);
    f32x4 obH = *(const f32x4*)(out_b + 64 + rlo);

    const ushort* xb = xin + (size_t)b * LL * 64;
    ushort* xo = xout + (size_t)b * LL * 64;
    int16_t* sb = skip + (size_t)b * LL * 64;
    const float inv_s2 = 0.70710678118654752440f;

#define LOADB(DST, TT)                                                           \
    {                                                                            \
        const int l0_ = seg * SEG + (TT) * 16;                                   \
        _Pragma("unroll")                                                        \
        for (int tap = 0; tap < 3; ++tap) {                                      \
            int lx = l0_ + n + (tap - 1) * d;                                    \
            bool v = (lx >= 0) && (lx < LL);                                     \
            _Pragma("unroll")                                                    \
            for (int h = 0; h < 2; ++h) {                                        \
                bf16x8 bv = {0, 0, 0, 0, 0, 0, 0, 0};                            \
                if (v) bv = *(const bf16x8*)(xb + (size_t)lx * 64 + h * 32 + kg * 8); \
                DST[tap * 2 + h] = bv;                                           \
            }                                                                    \
        }                                                                        \
    }

#define LOADE(XV, SO, TT)                                                        \
    {                                                                            \
        size_t off_ = (size_t)(seg * SEG + (TT) * 16 + n) * 64 + rlo;            \
        XV = *(const ushort4*)(xb + off_);                                       \
        SO = *(const short4*)(sb + off_);                                        \
    }

#define BODY1(TT, BUF, SLOT, BF)                                                 \
    {                                                                            \
        f32x4 accL = {0.f, 0.f, 0.f, 0.f}, accH = {0.f, 0.f, 0.f, 0.f};          \
        _Pragma("unroll")                                                        \
        for (int s = 0; s < 6; ++s) {                                            \
            accL = __builtin_amdgcn_mfma_f32_16x16x32_bf16(A0[s], BF[s], accL, 0, 0, 0); \
            accH = __builtin_amdgcn_mfma_f32_16x16x32_bf16(A1[s], BF[s], accH, 0, 0, 0); \
        }                                                                        \
        const int lx0 = seg * SEG + (TT) * 16 + n;                               \
        float selL = (lx0 < d) ? 1.f : 0.f;                                      \
        float selR = (lx0 >= LL - d) ? 1.f : 0.f;                                \
        float uu[4];                                                             \
        _Pragma("unroll")                                                        \
        for (int j = 0; j < 4; ++j) {                                            \
            float lo = accL[j] + bF_lo[j] - selL * bL_lo[j] - selR * bR_lo[j];   \
            float hi = accH[j] + bF_hi[j] - selL * bL_hi[j] - selR * bR_hi[j];   \
            float tv = 1.f - 2.f / (1.f + __expf(2.f * lo));                     \
            float sv = 1.f / (1.f + __expf(-hi));                                \
            uu[j] = tv * sv;                                                     \
        }                                                                        \
        uint2 uq;                                                                \
        uq.x = cvtpk(uu[0], uu[1]);                                              \
        uq.y = cvtpk(uu[2], uu[3]);                                              \
        *(uint2*)&su[BUF][SLOT][n][rlo] = uq;                                    \
    }

#define BODY2(TT, BUF, SLOT, XV, SO)                                             \
    {                                                                            \
        bf16x8 Bp0 = *(const bf16x8*)&su[BUF][SLOT][n][kg * 8];                  \
        bf16x8 Bp1 = *(const bf16x8*)&su[BUF][SLOT][n][32 + kg * 8];             \
        f32x4 zL = {0.f, 0.f, 0.f, 0.f}, zH = {0.f, 0.f, 0.f, 0.f};              \
        zL = __builtin_amdgcn_mfma_f32_16x16x32_bf16(P0[0], Bp0, zL, 0, 0, 0);   \
        zH = __builtin_amdgcn_mfma_f32_16x16x32_bf16(P1[0], Bp0, zH, 0, 0, 0);   \
        zL = __builtin_amdgcn_mfma_f32_16x16x32_bf16(P0[1], Bp1, zL, 0, 0, 0);   \
        zH = __builtin_amdgcn_mfma_f32_16x16x32_bf16(P1[1], Bp1, zH, 0, 0, 0);   \
        const int lx0 = seg * SEG + (TT) * 16 + n;                               \
        size_t off = (size_t)lx0 * 64 + rlo;                                     \
        float f0 = (bf2f(XV.x) + zL[0] + obL[0]) * inv_s2;                       \
        float f1 = (bf2f(XV.y) + zL[1] + obL[1]) * inv_s2;                       \
        float f2 = (bf2f(XV.z) + zL[2] + obL[2]) * inv_s2;                       \
        float f3 = (bf2f(XV.w) + zL[3] + obL[3]) * inv_s2;                       \
        uint2 xn;                                                                \
        xn.x = cvtpk(f0, f1);                                                    \
        xn.y = cvtpk(f2, f3);                                                    \
        *(uint2*)(xo + off) = xn;                                                \
        short4 sn;                                                               \
        float v;                                                                 \
        v = fminf(fmaxf((float)SO.x * SSI + zH[0] + obH[0], -1.999f), 1.999f);   \
        sn.x = (short)__float2int_rn(v * SS);                                    \
        v = fminf(fmaxf((float)SO.y * SSI + zH[1] + obH[1], -1.999f), 1.999f);   \
        sn.y = (short)__float2int_rn(v * SS);                                    \
        v = fminf(fmaxf((float)SO.z * SSI + zH[2] + obH[2], -1.999f), 1.999f);   \
        sn.z = (short)__float2int_rn(v * SS);                                    \
        v = fminf(fmaxf((float)SO.w * SSI + zH[3] + obH[3], -1.999f), 1.999f);   \
        sn.w = (short)__float2int_rn(v * SS);                                    \
        *(short4*)(sb + off) = sn;                                               \
    }

    bf16x8 FA[6], FB[6];
    ushort4 xvA, xvB;
    short4 soA, soB;
    LOADB(FA, 0)
    LOADB(FB, 1)
    LOADE(xvA, soA, 0)
    LOADE(xvB, soB, 1)
    for (int t = 0; t < NT; t += 2) {
        const int buf = (t >> 1) & 1;
        const int ta = (t + 2 < NT) ? t + 2 : t;
        const int tb = (t + 3 < NT) ? t + 3 : t + 1;
        // phase 1: conv GEMMs + gate -> LDS; refill B-frags for next macro
        BODY1(t, buf, 0, FA)
        LOADB(FA, ta)
        BODY1(t + 1, buf, 1, FB)
        LOADB(FB, tb)
        asm volatile("s_waitcnt lgkmcnt(0)" ::: "memory");
        __builtin_amdgcn_s_barrier();
        asm volatile("" ::: "memory");
        // phase 2: proj GEMMs + epilogue; refill epilogue operands
        BODY2(t, buf, 0, xvA, soA)
        BODY2(t + 1, buf, 1, xvB, soB)
        LOADE(xvA, soA, ta)
        LOADE(xvB, soB, tb)
    }
#undef LOADB
#undef LOADE
#undef BODY1
#undef BODY2
}

// ---------------- output head (MFMA, exact int16 hi/lo split) ----------------
__global__ __launch_bounds__(256) void head_mfma(const int16_t* __restrict__ skip,
                                                 const ushort* __restrict__ Wo1B,  // [4][2][64][8]
                                                 const float* __restrict__ bo1,
                                                 const float* __restrict__ Wo2,
                                                 const float* __restrict__ bo2,
                                                 float* __restrict__ out) {
    const int b = blockIdx.y;
    const int seg = blockIdx.x;  // 1024-pos segment
    const int tid = threadIdx.x;
    const int lane = tid & 63;
    const int w = tid >> 6;
    const int n = lane & 15;
    const int kg = lane >> 4;

    bf16x8 A[4][2];
    #pragma unroll
    for (int mt = 0; mt < 4; ++mt)
        #pragma unroll
        for (int s = 0; s < 2; ++s)
            A[mt][s] = *(const bf16x8*)(Wo1B + ((size_t)(mt * 2 + s) * 64 + lane) * 8);
    f32x4 bo1v[4], wo2v[4];
    #pragma unroll
    for (int mt = 0; mt < 4; ++mt) {
        bo1v[mt] = *(const f32x4*)(bo1 + mt * 16 + kg * 4);
        wo2v[mt] = *(const f32x4*)(Wo2 + mt * 16 + kg * 4);
    }
    const float bo2v = bo2[0];
    const int16_t* sb = skip + (size_t)b * LL * 64;

    for (int t = 0; t < 16; ++t) {
        const int l0 = seg * 1024 + t * 64 + w * 16;
        bf16x8 BH[2], BL[2];
        #pragma unroll
        for (int s = 0; s < 2; ++s) {
            s16x8 v = *(const s16x8*)(sb + (size_t)(l0 + n) * 64 + s * 32 + kg * 8);
            bf16x8 bh, bl;
            #pragma unroll
            for (int e = 0; e < 8; ++e) {
                int sv = (int)v[e];
                int h8 = sv >> 8;
                int l8 = sv - (h8 << 8);
                bh[e] = (short)f2bf((float)h8);
                bl[e] = (short)f2bf((float)l8);
            }
            BH[s] = bh;
            BL[s] = bl;
        }
        f32x4 aH[4], aL[4];
        #pragma unroll
        for (int mt = 0; mt < 4; ++mt) {
            aH[mt] = (f32x4){0.f, 0.f, 0.f, 0.f};
            aL[mt] = (f32x4){0.f, 0.f, 0.f, 0.f};
            #pragma unroll
            for (int s = 0; s < 2; ++s) {
                aH[mt] = __builtin_amdgcn_mfma_f32_16x16x32_bf16(A[mt][s], BH[s], aH[mt], 0, 0, 0);
                aL[mt] = __builtin_amdgcn_mfma_f32_16x16x32_bf16(A[mt][s], BL[s], aL[mt], 0, 0, 0);
            }
        }
        float partial = 0.f;
        #pragma unroll
        for (int mt = 0; mt < 4; ++mt) {
            #pragma unroll
            for (int j = 0; j < 4; ++j) {
                float h = aH[mt][j] * 256.f + aL[mt][j] + bo1v[mt][j];
                partial += (h > 0.f ? h : 0.f) * wo2v[mt][j];
            }
        }
        partial += __shfl_xor(partial, 16, 64);
        partial += __shfl_xor(partial, 32, 64);
        if (kg == 0) out[(size_t)b * LL + l0 + n] = partial + bo2v;
    }
}

extern "C" void kernel_launch(void* const* d_in, const int* in_sizes, int n_in,
                              void* d_out, int out_size, void* d_ws, size_t ws_size,
                              hipStream_t stream) {
    const float* audio = (const float*)d_in[0];
    const int* dstep = (const int*)d_in[1];
    const float* emb = (const float*)d_in[2];
    const float* W1 = (const float*)d_in[3];
    const float* b1 = (const float*)d_in[4];
    const float* W2 = (const float*)d_in[5];
    const float* b2 = (const float*)d_in[6];
    const float* Win = (const float*)d_in[7];
    const float* bin_ = (const float*)d_in[8];
    const float* diff_W = (const float*)d_in[9];
    const float* diff_b = (const float*)d_in[10];
    const float* dconv_W = (const float*)d_in[11];
    const float* dconv_b = (const float*)d_in[12];
    const float* out_W = (const float*)d_in[13];
    const float* out_b = (const float*)d_in[14];
    const float* Wo1 = (const float*)d_in[15];
    const float* bo1 = (const float*)d_in[16];
    const float* Wo2 = (const float*)d_in[17];
    const float* bo2 = (const float*)d_in[18];

    const size_t NACT = (size_t)BB * LL * 64;

    uint8_t* p = (uint8_t*)d_ws;
    ushort* x0 = (ushort*)p;     p += NACT * 2;
    ushort* x1 = (ushort*)p;     p += NACT * 2;
    int16_t* skip = (int16_t*)p; p += NACT * 2;
    float* t = (float*)p;        p += 8192 * 4;
    float* dp = (float*)p;       p += 30720 * 4;
    float* bias3 = (float*)p;    p += 184320 * 4;
    ushort* wB = (ushort*)p;     p += 737280 * 2;
    ushort* oB = (ushort*)p;     p += 245760 * 2;
    ushort* Wo1B = (ushort*)p;   p += 4096 * 2;

    hipMemsetAsync(skip, 0, NACT * 2, stream);
    emb_kernel<<<BB, 512, 0, stream>>>(dstep, emb, W1, b1, W2, b2, t);
    dp_kernel<<<dim3(NLAYERS, BB), 64, 0, stream>>>(t, diff_W, diff_b, dp);
    prep_w_kernel<<<2880, 256, 0, stream>>>(dconv_W, wB, out_W, oB, Wo1, Wo1B);
    bias3_kernel<<<dim3(NLAYERS, BB), 128, 0, stream>>>(dp, dconv_W, dconv_b, bias3);
    inproj_kernel<<<16384, 256, 0, stream>>>(audio, Win, bin_, x0);

    dim3 lgrid(LL / SEG, BB);
    ushort* xin = x0;
    ushort* xout = x1;
    for (int i = 0; i < NLAYERS; ++i) {
        int d = 1 << (i % 10);
        layer_fused<<<lgrid, 256, 0, stream>>>(
            xin, xout, skip, wB + (size_t)i * 24576, oB + (size_t)i * 8192,
            bias3 + (size_t)i * BB * 384, out_b + i * 128, d);
        ushort* tmp = xin; xin = xout; xout = tmp;
    }
    head_mfma<<<dim3(LL / 1024, BB), 256, 0, stream>>>(skip, Wo1B, bo1, Wo2, bo2,
                                                       (float*)d_out);
}

// Round 11
// 4504.254 us; speedup vs baseline: 2.7532x; 1.0278x over previous
//
#include <hip/hip_runtime.h>
#include <hip/hip_bf16.h>
#include <math.h>
#include <stdint.h>

#define NLAYERS 30
#define BB 16
#define LL 32768
#define SEG 256
#define NT (SEG / 16)

#define SS 16384.0f
#define SSI (1.0f / 16384.0f)

typedef __attribute__((ext_vector_type(8))) short bf16x8;
typedef __attribute__((ext_vector_type(8))) short s16x8;
typedef __attribute__((ext_vector_type(4))) float f32x4;

__device__ inline float bf2f(ushort u) {
    union { uint i; float f; } v; v.i = ((uint)u) << 16; return v.f;
}
__device__ inline ushort f2bf(float f) {  // RNE
    uint u = __float_as_uint(f);
    return (ushort)((u + 0x7FFFu + ((u >> 16) & 1u)) >> 16);
}
__device__ inline uint cvtpk(float lo, float hi) {  // (bf16(hi)<<16)|bf16(lo)
    uint r;
    asm("v_cvt_pk_bf16_f32 %0, %1, %2" : "=v"(r) : "v"(lo), "v"(hi));
    return r;
}

// ---------------- embedding MLP: t[b,512] ----------------
__global__ void emb_kernel(const int* __restrict__ step, const float* __restrict__ emb,
                           const float* __restrict__ W1, const float* __restrict__ b1,
                           const float* __restrict__ W2, const float* __restrict__ b2,
                           float* __restrict__ t_out) {
    int b = blockIdx.x, j = threadIdx.x;
    __shared__ float e[128];
    __shared__ float t1[512];
    int s = step[b];
    if (j < 128) e[j] = emb[s * 128 + j];
    __syncthreads();
    float acc = b1[j];
    const float* w = W1 + j * 128;
    for (int k = 0; k < 128; ++k) acc += w[k] * e[k];
    t1[j] = acc / (1.f + __expf(-acc));
    __syncthreads();
    float acc2 = b2[j];
    const float* w2 = W2 + j * 512;
    for (int k = 0; k < 512; ++k) acc2 += w2[k] * t1[k];
    t_out[b * 512 + j] = acc2 / (1.f + __expf(-acc2));
}

// ---------------- dp[i,b,c] = t[b] . diff_W[i,c,:] + diff_b[i,c] ----------------
__global__ void dp_kernel(const float* __restrict__ t, const float* __restrict__ diff_W,
                          const float* __restrict__ diff_b, float* __restrict__ dp) {
    int i = blockIdx.x, b = blockIdx.y, c = threadIdx.x;  // 64 threads
    __shared__ float ts[512];
    for (int k = c; k < 512; k += 64) ts[k] = t[b * 512 + k];
    __syncthreads();
    const float* w = diff_W + (size_t)(i * 64 + c) * 512;
    float acc = diff_b[i * 64 + c];
    for (int k = 0; k < 512; ++k) acc += w[k] * ts[k];
    dp[(i * BB + b) * 64 + c] = acc;
}

// ---------------- weight shuffles into MFMA fragment order (bf16) ----------------
__global__ void prep_w_kernel(const float* __restrict__ dconv_W, ushort* __restrict__ wB,
                              const float* __restrict__ out_W, ushort* __restrict__ oB,
                              const float* __restrict__ Wo1, ushort* __restrict__ Wo1B) {
    int idx = blockIdx.x * 256 + threadIdx.x;
    if (idx < 30 * 8 * 6 * 512) {
        int i = idx / 24576;
        int r = idx % 24576;
        int mt = r / 3072;
        int s = (r / 512) % 6;
        int lane = (r >> 3) & 63;
        int j = r & 7;
        int o = mt * 16 + (lane & 15);
        int tap = s >> 1;
        int c = (s & 1) * 32 + (lane >> 4) * 8 + j;
        wB[idx] = f2bf(dconv_W[((size_t)(i * 128 + o) * 64 + c) * 3 + tap]);
    }
    if (idx < 30 * 8 * 2 * 512) {
        int i = idx / 8192;
        int r = idx % 8192;
        int mt = r / 1024;
        int s = (r / 512) % 2;
        int lane = (r >> 3) & 63;
        int j = r & 7;
        int o = mt * 16 + (lane & 15);
        int c = s * 32 + (lane >> 4) * 8 + j;
        oB[idx] = f2bf(out_W[(size_t)(i * 128 + o) * 64 + c]);
    }
    if (idx < 4 * 2 * 512) {
        int mt = idx / 1024;
        int s = (idx / 512) % 2;
        int lane = (idx >> 3) & 63;
        int j = idx & 7;
        int o = mt * 16 + (lane & 15);
        int c = s * 32 + (lane >> 4) * 8 + j;
        const float hscale = SSI * 0.18257418583505537115f;  // SSI / sqrt(30)
        Wo1B[idx] = f2bf(Wo1[o * 64 + c] * hscale);
    }
}

// ---------------- bias3[i][b][{full,left,right}][128] ----------------
__global__ void bias3_kernel(const float* __restrict__ dp, const float* __restrict__ dconv_W,
                             const float* __restrict__ dconv_b, float* __restrict__ bias3) {
    int i = blockIdx.x, b = blockIdx.y, o = threadIdx.x;  // 128 threads
    __shared__ float sdp[64];
    if (o < 64) sdp[o] = dp[(i * BB + b) * 64 + o];
    __syncthreads();
    const float* wrow = dconv_W + (size_t)(i * 128 + o) * 192;
    float f = 0.f, lft = 0.f, rgt = 0.f;
    for (int c = 0; c < 64; ++c) {
        float w0 = wrow[c * 3 + 0], w1 = wrow[c * 3 + 1], w2 = wrow[c * 3 + 2];
        float dv = sdp[c];
        f += dv * (w0 + w1 + w2);
        lft += dv * w0;
        rgt += dv * w2;
    }
    float* dst = bias3 + (size_t)(i * BB + b) * 384;
    dst[o] = f + dconv_b[i * 128 + o];
    dst[128 + o] = lft;
    dst[256 + o] = rgt;
}

// ---------------- input projection -> x[b][l][c] bf16 ----------------
__global__ void inproj_kernel(const float* __restrict__ audio, const float* __restrict__ Win,
                              const float* __restrict__ bin_, ushort* __restrict__ x) {
    int idx = blockIdx.x * 256 + threadIdx.x;  // B*L*8
    int c8 = idx & 7;
    int l = (idx >> 3) & (LL - 1);
    int b = idx >> 18;
    float a = audio[(size_t)b * LL + l];
    ushort us[8];
    #pragma unroll
    for (int cc = 0; cc < 8; ++cc) {
        int c = c8 * 8 + cc;
        float v = a * Win[c] + bin_[c];
        us[cc] = f2bf(v > 0.f ? v : 0.f);
    }
    ushort4* dst = (ushort4*)(x + ((size_t)b * LL + l) * 64 + c8 * 8);
    dst[0] = make_ushort4(us[0], us[1], us[2], us[3]);
    dst[1] = make_ushort4(us[4], us[5], us[6], us[7]);
}

// ---------------- fused residual layer: 2 sub-tiles per barrier, pipelined ----------------
__global__ __launch_bounds__(256) void layer_fused(
    const ushort* __restrict__ xin, ushort* __restrict__ xout, int16_t* __restrict__ skip,
    const ushort* __restrict__ wB,    // [8][6][64][8] this layer
    const ushort* __restrict__ oB,    // [8][2][64][8] this layer
    const float* __restrict__ bias3,  // [16][3][128] this layer
    const float* __restrict__ out_b,  // [128]
    int d) {
    __shared__ __align__(16) ushort su[2][2][16][72];  // [buf][slot][pos][ch]

    const int b = blockIdx.y;
    const int seg = blockIdx.x;

    const int tid = threadIdx.x;
    const int lane = tid & 63;
    const int p = tid >> 6;
    const int n = lane & 15;
    const int kg = lane >> 4;
    const int rlo = p * 16 + kg * 4;

    bf16x8 A0[6], A1[6], P0[2], P1[2];
    #pragma unroll
    for (int s = 0; s < 6; ++s) {
        A0[s] = *(const bf16x8*)(wB + ((size_t)(p * 6 + s) * 64 + lane) * 8);
        A1[s] = *(const bf16x8*)(wB + ((size_t)((p + 4) * 6 + s) * 64 + lane) * 8);
    }
    #pragma unroll
    for (int s = 0; s < 2; ++s) {
        P0[s] = *(const bf16x8*)(oB + ((size_t)(p * 2 + s) * 64 + lane) * 8);
        P1[s] = *(const bf16x8*)(oB + ((size_t)((p + 4) * 2 + s) * 64 + lane) * 8);
    }
    const float* bb = bias3 + (size_t)b * 384;
    f32x4 bF_lo = *(const f32x4*)(bb + rlo);
    f32x4 bF_hi = *(const f32x4*)(bb + 64 + rlo);
    f32x4 bL_lo = *(const f32x4*)(bb + 128 + rlo);
    f32x4 bL_hi = *(const f32x4*)(bb + 192 + rlo);
    f32x4 bR_lo = *(const f32x4*)(bb + 256 + rlo);
    f32x4 bR_hi = *(const f32x4*)(bb + 320 + rlo);
    f32x4 obL = *(const f32x4*)(out_b + rlo);
    f32x4 obH = *(const f32x4*)(out_b + 64 + rlo);

    const ushort* xb = xin + (size_t)b * LL * 64;
    ushort* xo = xout + (size_t)b * LL * 64;
    int16_t* sb = skip + (size_t)b * LL * 64;
    const float inv_s2 = 0.70710678118654752440f;

#define LOADB(DST, TT)                                                           \
    {                                                                            \
        const int l0_ = seg * SEG + (TT) * 16;                                   \
        _Pragma("unroll")                                                        \
        for (int tap = 0; tap < 3; ++tap) {                                      \
            int lx = l0_ + n + (tap - 1) * d;                                    \
            bool v = (lx >= 0) && (lx < LL);                                     \
            _Pragma("unroll")                                                    \
            for (int h = 0; h < 2; ++h) {                                        \
                bf16x8 bv = {0, 0, 0, 0, 0, 0, 0, 0};                            \
                if (v) bv = *(const bf16x8*)(xb + (size_t)lx * 64 + h * 32 + kg * 8); \
                DST[tap * 2 + h] = bv;                                           \
            }                                                                    \
        }                                                                        \
    }

#define LOADE(XV, SO, TT)                                                        \
    {                                                                            \
        size_t off_ = (size_t)(seg * SEG + (TT) * 16 + n) * 64 + rlo;            \
        XV = *(const ushort4*)(xb + off_);                                       \
        SO = *(const short4*)(sb + off_);                                        \
    }

#define BODY1(TT, BUF, SLOT, BF)                                                 \
    {                                                                            \
        f32x4 accL = {0.f, 0.f, 0.f, 0.f}, accH = {0.f, 0.f, 0.f, 0.f};          \
        __builtin_amdgcn_s_setprio(1);                                           \
        _Pragma("unroll")                                                        \
        for (int s = 0; s < 6; ++s) {                                            \
            accL = __builtin_amdgcn_mfma_f32_16x16x32_bf16(A0[s], BF[s], accL, 0, 0, 0); \
            accH = __builtin_amdgcn_mfma_f32_16x16x32_bf16(A1[s], BF[s], accH, 0, 0, 0); \
        }                                                                        \
        __builtin_amdgcn_s_setprio(0);                                           \
        const int lx0 = seg * SEG + (TT) * 16 + n;                               \
        float selL = (lx0 < d) ? 1.f : 0.f;                                      \
        float selR = (lx0 >= LL - d) ? 1.f : 0.f;                                \
        float uu[4];                                                             \
        _Pragma("unroll")                                                        \
        for (int j = 0; j < 4; ++j) {                                            \
            float lo = accL[j] + bF_lo[j] - selL * bL_lo[j] - selR * bR_lo[j];   \
            float hi = accH[j] + bF_hi[j] - selL * bL_hi[j] - selR * bR_hi[j];   \
            float tv = 1.f - 2.f * __builtin_amdgcn_rcpf(1.f + __expf(2.f * lo)); \
            float sv = __builtin_amdgcn_rcpf(1.f + __expf(-hi));                 \
            uu[j] = tv * sv;                                                     \
        }                                                                        \
        uint2 uq;                                                                \
        uq.x = cvtpk(uu[0], uu[1]);                                              \
        uq.y = cvtpk(uu[2], uu[3]);                                              \
        *(uint2*)&su[BUF][SLOT][n][rlo] = uq;                                    \
    }

#define BODY2(TT, BUF, SLOT, XV, SO)                                             \
    {                                                                            \
        bf16x8 Bp0 = *(const bf16x8*)&su[BUF][SLOT][n][kg * 8];                  \
        bf16x8 Bp1 = *(const bf16x8*)&su[BUF][SLOT][n][32 + kg * 8];             \
        f32x4 zL = {0.f, 0.f, 0.f, 0.f}, zH = {0.f, 0.f, 0.f, 0.f};              \
        __builtin_amdgcn_s_setprio(1);                                           \
        zL = __builtin_amdgcn_mfma_f32_16x16x32_bf16(P0[0], Bp0, zL, 0, 0, 0);   \
        zH = __builtin_amdgcn_mfma_f32_16x16x32_bf16(P1[0], Bp0, zH, 0, 0, 0);   \
        zL = __builtin_amdgcn_mfma_f32_16x16x32_bf16(P0[1], Bp1, zL, 0, 0, 0);   \
        zH = __builtin_amdgcn_mfma_f32_16x16x32_bf16(P1[1], Bp1, zH, 0, 0, 0);   \
        __builtin_amdgcn_s_setprio(0);                                           \
        const int lx0 = seg * SEG + (TT) * 16 + n;                               \
        size_t off = (size_t)lx0 * 64 + rlo;                                     \
        float f0 = (bf2f(XV.x) + zL[0] + obL[0]) * inv_s2;                       \
        float f1 = (bf2f(XV.y) + zL[1] + obL[1]) * inv_s2;                       \
        float f2 = (bf2f(XV.z) + zL[2] + obL[2]) * inv_s2;                       \
        float f3 = (bf2f(XV.w) + zL[3] + obL[3]) * inv_s2;                       \
        uint2 xn;                                                                \
        xn.x = cvtpk(f0, f1);                                                    \
        xn.y = cvtpk(f2, f3);                                                    \
        *(uint2*)(xo + off) = xn;                                                \
        short4 sn;                                                               \
        float v;                                                                 \
        v = fminf(fmaxf((float)SO.x * SSI + zH[0] + obH[0], -1.999f), 1.999f);   \
        sn.x = (short)__float2int_rn(v * SS);                                    \
        v = fminf(fmaxf((float)SO.y * SSI + zH[1] + obH[1], -1.999f), 1.999f);   \
        sn.y = (short)__float2int_rn(v * SS);                                    \
        v = fminf(fmaxf((float)SO.z * SSI + zH[2] + obH[2], -1.999f), 1.999f);   \
        sn.z = (short)__float2int_rn(v * SS);                                    \
        v = fminf(fmaxf((float)SO.w * SSI + zH[3] + obH[3], -1.999f), 1.999f);   \
        sn.w = (short)__float2int_rn(v * SS);                                    \
        *(short4*)(sb + off) = sn;                                               \
    }

    bf16x8 FA[6], FB[6];
    ushort4 xvA, xvB;
    short4 soA, soB;
    LOADB(FA, 0)
    LOADB(FB, 1)
    LOADE(xvA, soA, 0)
    LOADE(xvB, soB, 1)
    for (int t = 0; t < NT; t += 2) {
        const int buf = (t >> 1) & 1;
        const int ta = (t + 2 < NT) ? t + 2 : t;
        const int tb = (t + 3 < NT) ? t + 3 : t + 1;
        // phase 1: conv GEMMs + gate -> LDS; refill B-frags for next macro
        BODY1(t, buf, 0, FA)
        LOADB(FA, ta)
        BODY1(t + 1, buf, 1, FB)
        LOADB(FB, tb)
        asm volatile("s_waitcnt lgkmcnt(0)" ::: "memory");
        __builtin_amdgcn_s_barrier();
        asm volatile("" ::: "memory");
        // phase 2: proj GEMMs + epilogue; refill epilogue operands
        BODY2(t, buf, 0, xvA, soA)
        BODY2(t + 1, buf, 1, xvB, soB)
        LOADE(xvA, soA, ta)
        LOADE(xvB, soB, tb)
    }
#undef LOADB
#undef LOADE
#undef BODY1
#undef BODY2
}

// ---------------- output head (MFMA, exact int16 hi/lo split) ----------------
__global__ __launch_bounds__(256) void head_mfma(const int16_t* __restrict__ skip,
                                                 const ushort* __restrict__ Wo1B,  // [4][2][64][8]
                                                 const float* __restrict__ bo1,
                                                 const float* __restrict__ Wo2,
                                                 const float* __restrict__ bo2,
                                                 float* __restrict__ out) {
    const int b = blockIdx.y;
    const int seg = blockIdx.x;  // 1024-pos segment
    const int tid = threadIdx.x;
    const int lane = tid & 63;
    const int w = tid >> 6;
    const int n = lane & 15;
    const int kg = lane >> 4;

    bf16x8 A[4][2];
    #pragma unroll
    for (int mt = 0; mt < 4; ++mt)
        #pragma unroll
        for (int s = 0; s < 2; ++s)
            A[mt][s] = *(const bf16x8*)(Wo1B + ((size_t)(mt * 2 + s) * 64 + lane) * 8);
    f32x4 bo1v[4], wo2v[4];
    #pragma unroll
    for (int mt = 0; mt < 4; ++mt) {
        bo1v[mt] = *(const f32x4*)(bo1 + mt * 16 + kg * 4);
        wo2v[mt] = *(const f32x4*)(Wo2 + mt * 16 + kg * 4);
    }
    const float bo2v = bo2[0];
    const int16_t* sb = skip + (size_t)b * LL * 64;

    for (int t = 0; t < 16; ++t) {
        const int l0 = seg * 1024 + t * 64 + w * 16;
        bf16x8 BH[2], BL[2];
        #pragma unroll
        for (int s = 0; s < 2; ++s) {
            s16x8 v = *(const s16x8*)(sb + (size_t)(l0 + n) * 64 + s * 32 + kg * 8);
            bf16x8 bh, bl;
            #pragma unroll
            for (int e = 0; e < 8; ++e) {
                int sv = (int)v[e];
                int h8 = sv >> 8;
                int l8 = sv - (h8 << 8);
                bh[e] = (short)f2bf((float)h8);
                bl[e] = (short)f2bf((float)l8);
            }
            BH[s] = bh;
            BL[s] = bl;
        }
        f32x4 aH[4], aL[4];
        #pragma unroll
        for (int mt = 0; mt < 4; ++mt) {
            aH[mt] = (f32x4){0.f, 0.f, 0.f, 0.f};
            aL[mt] = (f32x4){0.f, 0.f, 0.f, 0.f};
            #pragma unroll
            for (int s = 0; s < 2; ++s) {
                aH[mt] = __builtin_amdgcn_mfma_f32_16x16x32_bf16(A[mt][s], BH[s], aH[mt], 0, 0, 0);
                aL[mt] = __builtin_amdgcn_mfma_f32_16x16x32_bf16(A[mt][s], BL[s], aL[mt], 0, 0, 0);
            }
        }
        float partial = 0.f;
        #pragma unroll
        for (int mt = 0; mt < 4; ++mt) {
            #pragma unroll
            for (int j = 0; j < 4; ++j) {
                float h = aH[mt][j] * 256.f + aL[mt][j] + bo1v[mt][j];
                partial += (h > 0.f ? h : 0.f) * wo2v[mt][j];
            }
        }
        partial += __shfl_xor(partial, 16, 64);
        partial += __shfl_xor(partial, 32, 64);
        if (kg == 0) out[(size_t)b * LL + l0 + n] = partial + bo2v;
    }
}

extern "C" void kernel_launch(void* const* d_in, const int* in_sizes, int n_in,
                              void* d_out, int out_size, void* d_ws, size_t ws_size,
                              hipStream_t stream) {
    const float* audio = (const float*)d_in[0];
    const int* dstep = (const int*)d_in[1];
    const float* emb = (const float*)d_in[2];
    const float* W1 = (const float*)d_in[3];
    const float* b1 = (const float*)d_in[4];
    const float* W2 = (const float*)d_in[5];
    const float* b2 = (const float*)d_in[6];
    const float* Win = (const float*)d_in[7];
    const float* bin_ = (const float*)d_in[8];
    const float* diff_W = (const float*)d_in[9];
    const float* diff_b = (const float*)d_in[10];
    const float* dconv_W = (const float*)d_in[11];
    const float* dconv_b = (const float*)d_in[12];
    const float* out_W = (const float*)d_in[13];
    const float* out_b = (const float*)d_in[14];
    const float* Wo1 = (const float*)d_in[15];
    const float* bo1 = (const float*)d_in[16];
    const float* Wo2 = (const float*)d_in[17];
    const float* bo2 = (const float*)d_in[18];

    const size_t NACT = (size_t)BB * LL * 64;

    uint8_t* p = (uint8_t*)d_ws;
    ushort* x0 = (ushort*)p;     p += NACT * 2;
    ushort* x1 = (ushort*)p;     p += NACT * 2;
    int16_t* skip = (int16_t*)p; p += NACT * 2;
    float* t = (float*)p;        p += 8192 * 4;
    float* dp = (float*)p;       p += 30720 * 4;
    float* bias3 = (float*)p;    p += 184320 * 4;
    ushort* wB = (ushort*)p;     p += 737280 * 2;
    ushort* oB = (ushort*)p;     p += 245760 * 2;
    ushort* Wo1B = (ushort*)p;   p += 4096 * 2;

    hipMemsetAsync(skip, 0, NACT * 2, stream);
    emb_kernel<<<BB, 512, 0, stream>>>(dstep, emb, W1, b1, W2, b2, t);
    dp_kernel<<<dim3(NLAYERS, BB), 64, 0, stream>>>(t, diff_W, diff_b, dp);
    prep_w_kernel<<<2880, 256, 0, stream>>>(dconv_W, wB, out_W, oB, Wo1, Wo1B);
    bias3_kernel<<<dim3(NLAYERS, BB), 128, 0, stream>>>(dp, dconv_W, dconv_b, bias3);
    inproj_kernel<<<16384, 256, 0, stream>>>(audio, Win, bin_, x0);

    dim3 lgrid(LL / SEG, BB);
    ushort* xin = x0;
    ushort* xout = x1;
    for (int i = 0; i < NLAYERS; ++i) {
        int d = 1 << (i % 10);
        layer_fused<<<lgrid, 256, 0, stream>>>(
            xin, xout, skip, wB + (size_t)i * 24576, oB + (size_t)i * 8192,
            bias3 + (size_t)i * BB * 384, out_b + i * 128, d);
        ushort* tmp = xin; xin = xout; xout = tmp;
    }
    head_mfma<<<dim3(LL / 1024, BB), 256, 0, stream>>>(skip, Wo1B, bo1, Wo2, bo2,
                                                       (float*)d_out);
}